// Round 2
// baseline (204.208 us; speedup 1.0000x reference)
//
#include <hip/hip_runtime.h>
#include <stdint.h>
#include <stddef.h>

#define BATCH 16
#define SEQ 2048
#define HDIM 256
#define SCHUNK 32
#define TTILE 128
#define NCHUNK 64            // SEQ / SCHUNK
#define TILE_U16 8192        // 16 KB tile (32 x 256 halves)
#define NTILES 1024          // BATCH * NCHUNK
#define PREBLK 2048          // 2 half-blocks per tile
#define KSTRIDE 260          // prepass fp32 staging row stride (bank stride 4)
#define PSTRIDE 40           // P row stride in u16

typedef float f32x4 __attribute__((ext_vector_type(4)));
typedef float f32x16 __attribute__((ext_vector_type(16)));
typedef _Float16 f16x8 __attribute__((ext_vector_type(8)));
typedef __bf16 bf16x8 __attribute__((ext_vector_type(8)));
typedef unsigned short u16;
typedef u16 u16x4 __attribute__((ext_vector_type(4)));
typedef u16 u16x8 __attribute__((ext_vector_type(8)));
typedef unsigned int u32;
typedef u32 u32x2 __attribute__((ext_vector_type(2)));
typedef const __attribute__((address_space(1))) u32* gp1_t;
typedef __attribute__((address_space(3))) u32* lp3_t;

static __device__ __forceinline__ u16 f2bf(float f) {
  union { float f; unsigned int u; } v; v.f = f;
  unsigned int u = v.u;
  unsigned int r = u + 0x7FFFu + ((u >> 16) & 1u);  // RNE
  return (u16)(r >> 16);
}

// ============================================================================
// Pre-pass: enc [S,B,2H] fp32 -> fragment-ordered tiles per (b,chunk):
//   KH (fp16):  [kb 0..15][lane(m,g)][j] = K[s=m][h=kb*16+g*8+j]   (QK A-op)
//   VT (bf16):  [ht*2+ka][lane][j]      = K[s=ka*16+g*8+j][h=ht*32+m] (PV B-op)
// Each block handles HALF a tile (16 s-rows) -> 2048 blocks, 16.6 KB LDS.
// ============================================================================
__global__ __launch_bounds__(256, 8)
void prepass_kernel(const float* __restrict__ e,
                    u16* __restrict__ KH, u16* __restrict__ VT) {
  __shared__ float Ks[16 * KSTRIDE];   // 16 rows only: 16,640 B
  const int tid = threadIdx.x;
  const int bid = blockIdx.x;
  const int h2  = bid & 1;             // which 16-row half of the chunk
  const int tb  = bid >> 1;            // tile id 0..1023
  const int b   = tb >> 6;
  const int ck  = tb & 63;
  const size_t tile = (size_t)tb * TILE_U16;
  const int r0 = h2 * 16;

  {
    int row = tid >> 4;                // 0..15
    int c16 = tid & 15;                // 0..15
    const float* src = e + ((size_t)(ck * SCHUNK + r0 + row) * BATCH + b) * (2 * HDIM);
#pragma unroll
    for (int u = 0; u < 4; ++u) {
      int col = c16 * 4 + 64 * u;
      float4 xa = *(const float4*)(src + col);
      float4 xb = *(const float4*)(src + col + HDIM);
      float4 s; s.x = xa.x + xb.x; s.y = xa.y + xb.y; s.z = xa.z + xb.z; s.w = xa.w + xb.w;
      *(float4*)&Ks[row * KSTRIDE + col] = s;
    }
  }
  __syncthreads();

  const int lane = tid & 63;
  const int w = tid >> 6;              // 0..3

  // ---- KH: wave w covers kb = 4w + 2i + (lane>=32); our block owns m in [r0,r0+16)
  {
    int half = lane >> 5;
    int l5   = lane & 31;
    int lm   = l5 & 15;                // m - r0
    int g    = (l5 >> 4) & 1;
#pragma unroll
    for (int i = 0; i < 2; ++i) {
      int kb = w * 4 + i * 2 + half;
      const float* rp = &Ks[lm * KSTRIDE + kb * 16 + g * 8];
      u16x8 hi;
#pragma unroll
      for (int j = 0; j < 8; ++j)
        hi[j] = __builtin_bit_cast(u16, (_Float16)rp[j]);
      int lane_out = g * 32 + r0 + lm;
      *(u16x8*)&KH[tile + (size_t)(kb * 64 + lane_out) * 8] = hi;
    }
  }

  // ---- VT: our block owns exactly ka = h2; wave w covers ht = 2w + i
  {
    int m = lane & 31;
    int g = lane >> 5;
#pragma unroll
    for (int i = 0; i < 2; ++i) {
      int ht = w * 2 + i;
      int fr = ht * 2 + h2;
      u16x8 v;
#pragma unroll
      for (int j = 0; j < 8; ++j)
        v[j] = f2bf(Ks[(g * 8 + j) * KSTRIDE + ht * 32 + m]);
      *(u16x8*)&VT[tile + (size_t)(fr * 64 + lane) * 8] = v;
    }
  }
}

// ============================================================================
// Main: 512 threads (8 waves, 1 block/CU). Source-split: waves 0-3 even
// chunks, 4-7 odd chunks, same 128 targets. 4 resident chunk buffers.
// NEW this round (T3/T4 counted-vmcnt pipeline, m201-template pattern):
//   - stage(j+1) issued FIRST, then s_waitcnt vmcnt(8) (waits only pair-j's
//     8 oldest loads; pair-(j+1)'s 8 stay in flight across both barriers
//     and the whole compute phase -> latency hidden)
//   - raw s_barrier pair per iteration instead of __syncthreads (no vmcnt(0)
//     drain in the main loop); barrier#2 seals pair-j reads before the
//     next iteration's stage overwrites those buffers.
//   - sched_barrier(0) fences pin the compute phase (rule #18 hoisting).
// ============================================================================
__global__ __launch_bounds__(512, 2)
void attn_main_kernel(const u16* __restrict__ KH, const u16* __restrict__ VT,
                      const float* __restrict__ dq,  // [T, B, H]
                      float* __restrict__ out) {     // [T, B, H]
  __shared__ alignas(16) u16 KHs[4][TILE_U16];   // 64 KB
  __shared__ alignas(16) u16 VTs[4][TILE_U16];   // 64 KB
  __shared__ alignas(16) u16 Pb[8][32 * PSTRIDE]; // 20 KB

  const int tid  = threadIdx.x;
  const int lane = tid & 63;
  const int wv   = tid >> 6;        // 0..7
  const int wq   = wv & 3;          // target-group 0..3
  const int grp  = wv >> 2;         // 0 = even chunks, 1 = odd chunks
  const int m    = lane & 31;
  const int g    = lane >> 5;

  // XCD-aware swizzle: hw assigns XCD = blockIdx % 8 (round-robin).
  // XCD x gets batches {2x, 2x+1}: K/V working set = 4MB ~= L2.
  const int bid = blockIdx.x;
  const int b  = ((bid & 7) << 1) | ((bid >> 3) & 1);
  const int t0 = (bid >> 4) * TTILE;

  // ---- Q fragments fp16 (B-operand: B[k=g*8+j][n=m]) ----
  const int tq = t0 + wq * 32 + m;
  const float* qp = dq + ((size_t)tq * BATCH + b) * HDIM;
  f16x8 qh[16];
#pragma unroll
  for (int kb = 0; kb < 16; ++kb) {
    int h = kb * 16 + g * 8;
    float4 f0 = *(const float4*)(qp + h);
    float4 f1 = *(const float4*)(qp + h + 4);
    float xs[8] = {f0.x, f0.y, f0.z, f0.w, f1.x, f1.y, f1.z, f1.w};
    u16x8 hb;
#pragma unroll
    for (int j = 0; j < 8; ++j)
      hb[j] = __builtin_bit_cast(u16, (_Float16)xs[j]);
    qh[kb] = __builtin_bit_cast(f16x8, hb);
  }

  f32x16 ctx[8];
#pragma unroll
  for (int ht = 0; ht < 8; ++ht) ctx[ht] = (f32x16)(0.0f);
  float dsum = 0.0f;

  // ---- staging: wave wv owns 8 KB of the 64 KB pair-stage ----
  // wv 0,1: KH of chunk 2j+0|  wv 2,3: VT of 2j+0 | wv 4,5: KH 2j+1 | wv 6,7: VT 2j+1
  const bool isVT  = (wv >> 1) & 1;
  const int  choff = wv >> 2;
  const int  subbase = (wv & 1) * 8;
  const u16* srcArr = isVT ? VT : KH;
  auto stage = [&](int jpair) {
    int ckk = 2 * jpair + choff;
    int buf = ckk & 3;
    size_t tb = ((size_t)b * NCHUNK + ckk) * TILE_U16;
    u16* dst = isVT ? &VTs[buf][0] : &KHs[buf][0];
#pragma unroll
    for (int i = 0; i < 8; ++i) {
      int sub = subbase + i;
      __builtin_amdgcn_global_load_lds(
          (gp1_t)(const void*)&srcArr[tb + (size_t)sub * 512 + lane * 8],
          (lp3_t)(void*)&dst[sub * 512], 16, 0, 0);
    }
  };

  stage(0);

  for (int j = 0; j < 32; ++j) {
    // Issue next pair's loads FIRST (targets pair-(j+1) bufs, disjoint from
    // pair j; pair-(j-1) reads were sealed by barrier#2 of iter j-1).
    if (j < 31) {
      stage(j + 1);
      // Wait only the 8 OLDEST loads (= my pair-j stage); the 8 just issued
      // stay in flight across the barrier and the whole compute phase.
      asm volatile("s_waitcnt vmcnt(8)" ::: "memory");
    } else {
      asm volatile("s_waitcnt vmcnt(0)" ::: "memory");
    }
    __builtin_amdgcn_s_barrier();      // all waves: pair-j staging complete
    __builtin_amdgcn_sched_barrier(0);

    const int ckk = 2 * j + grp;     // this wave's chunk
    const int buf = ckk & 3;

    // ---- QK^T as S^T (m=s, n=t), fp16, two independent chains ----
    f32x16 a0 = (f32x16)(0.0f), a1 = (f32x16)(0.0f);
    __builtin_amdgcn_s_setprio(1);
#pragma unroll
    for (int kb = 0; kb < 16; kb += 2) {
      f16x8 k0 = __builtin_bit_cast(f16x8, *(const u16x8*)&KHs[buf][kb * 512 + lane * 8]);
      f16x8 k1 = __builtin_bit_cast(f16x8, *(const u16x8*)&KHs[buf][(kb + 1) * 512 + lane * 8]);
      a0 = __builtin_amdgcn_mfma_f32_32x32x16_f16(k0, qh[kb], a0, 0, 0, 0);
      a1 = __builtin_amdgcn_mfma_f32_32x32x16_f16(k1, qh[kb + 1], a1, 0, 0, 0);
    }
    __builtin_amdgcn_s_setprio(0);

    // ---- exp(s-128), denom, pack bf16 via v_cvt_pk, P -> LDS ----
    float pf[16];
#pragma unroll
    for (int r = 0; r < 16; ++r) {
      pf[r] = __expf(a0[r] + a1[r] - 128.0f);
      dsum += pf[r];
    }
    u32 pk[8];
#pragma unroll
    for (int q = 0; q < 8; ++q)
      asm("v_cvt_pk_bf16_f32 %0, %1, %2"
          : "=v"(pk[q]) : "v"(pf[2 * q]), "v"(pf[2 * q + 1]));
#pragma unroll
    for (int rr = 0; rr < 4; ++rr) {
      u32x2 w2 = {pk[2 * rr], pk[2 * rr + 1]};
      *(u32x2*)&Pb[wv][m * PSTRIDE + rr * 8 + g * 4] = w2;   // s = 8rr+4g+0..3
    }
    bf16x8 pa0 = __builtin_bit_cast(bf16x8, *(const u16x8*)&Pb[wv][m * PSTRIDE + g * 8]);
    bf16x8 pa1 = __builtin_bit_cast(bf16x8, *(const u16x8*)&Pb[wv][m * PSTRIDE + 16 + g * 8]);

    // ---- PV: ctx(m=t, n=h) += P * V ----
    __builtin_amdgcn_s_setprio(1);
#pragma unroll
    for (int ht = 0; ht < 8; ++ht) {
      bf16x8 v0 = __builtin_bit_cast(bf16x8, *(const u16x8*)&VTs[buf][(ht * 2) * 512 + lane * 8]);
      bf16x8 v1 = __builtin_bit_cast(bf16x8, *(const u16x8*)&VTs[buf][(ht * 2 + 1) * 512 + lane * 8]);
      ctx[ht] = __builtin_amdgcn_mfma_f32_32x32x16_bf16(pa0, v0, ctx[ht], 0, 0, 0);
      ctx[ht] = __builtin_amdgcn_mfma_f32_32x32x16_bf16(pa1, v1, ctx[ht], 0, 0, 0);
    }
    __builtin_amdgcn_s_setprio(0);

    __builtin_amdgcn_sched_barrier(0);
    __builtin_amdgcn_s_barrier();      // seal pair-j reads before overwrite
  }

  // ---- combine the two source-halves (exact: same exp offset) ----
  dsum += __shfl_xor(dsum, 32, 64);   // per-lane: partial denom for t = m
  __syncthreads();                     // full drain once; bufs reusable

  // exchange region for target-group wq: 32 KB each
  float* exch = (wq < 2) ? (float*)&KHs[wq * 2][0] : (float*)&VTs[(wq - 2) * 2][0];

  if (grp == 1) {
    // layout [r4][ht][lane][4]: b128, 2-way banks (free)
#pragma unroll
    for (int r4 = 0; r4 < 4; ++r4)
#pragma unroll
      for (int ht = 0; ht < 8; ++ht) {
        f32x4 v = {ctx[ht][r4 * 4], ctx[ht][r4 * 4 + 1],
                   ctx[ht][r4 * 4 + 2], ctx[ht][r4 * 4 + 3]};
        *(f32x4*)&exch[r4 * 2048 + ht * 256 + lane * 4] = v;
      }
    ((float*)&Pb[wv][0])[lane] = dsum;
  }
  __syncthreads();

  if (grp == 0) {
    float dB = ((const float*)&Pb[wv + 4][0])[lane];
    float inv = 1.0f / (dsum + dB);
#pragma unroll
    for (int r4 = 0; r4 < 4; ++r4)
#pragma unroll
      for (int ht = 0; ht < 8; ++ht) {
        f32x4 v = *(const f32x4*)&exch[r4 * 2048 + ht * 256 + lane * 4];
        ctx[ht][r4 * 4]     += v[0];
        ctx[ht][r4 * 4 + 1] += v[1];
        ctx[ht][r4 * 4 + 2] += v[2];
        ctx[ht][r4 * 4 + 3] += v[3];
      }
#pragma unroll
    for (int r = 0; r < 16; ++r) {
      int tl = (r & 3) + 8 * (r >> 2) + 4 * g;
      float rinv = __shfl(inv, tl, 64);
      int t = t0 + wq * 32 + tl;
      float* op = out + ((size_t)t * BATCH + b) * HDIM + m;
#pragma unroll
      for (int ht = 0; ht < 8; ++ht)
        op[ht * 32] = ctx[ht][r] * rinv;
    }
  }
}

extern "C" void kernel_launch(void* const* d_in, const int* in_sizes, int n_in,
                              void* d_out, int out_size, void* d_ws, size_t ws_size,
                              hipStream_t stream) {
  const float* e  = (const float*)d_in[0];  // out_e [2048, 16, 512]
  const float* dq = (const float*)d_in[1];  // out_d [2048, 16, 256]
  float* out = (float*)d_out;               // [2048, 16, 256]
  u16* KH = (u16*)d_ws;                                 // fp16 bits, 16 MB
  u16* VT = KH + (size_t)NTILES * TILE_U16;             // bf16 bits, 16 MB
  prepass_kernel<<<dim3(PREBLK), dim3(256), 0, stream>>>(e, KH, VT);
  attn_main_kernel<<<dim3(BATCH * (SEQ / TTILE)), dim3(512), 0, stream>>>(
      KH, VT, dq, out);
}

// Round 3
// 200.750 us; speedup vs baseline: 1.0172x; 1.0172x over previous
//
#include <hip/hip_runtime.h>
#include <stdint.h>
#include <stddef.h>

#define BATCH 16
#define SEQ 2048
#define HDIM 256
#define SCHUNK 32
#define TTILE 128
#define NCHUNK 64            // SEQ / SCHUNK
#define TILE_U16 8192        // 16 KB tile (32 x 256 halves)
#define NTILES 1024          // BATCH * NCHUNK
#define PREBLK 2048          // 2 half-blocks per tile
#define KSTRIDE 260          // prepass fp32 staging row stride (bank stride 4)

typedef float f32x4 __attribute__((ext_vector_type(4)));
typedef float f32x16 __attribute__((ext_vector_type(16)));
typedef _Float16 f16x8 __attribute__((ext_vector_type(8)));
typedef __bf16 bf16x8 __attribute__((ext_vector_type(8)));
typedef unsigned short u16;
typedef u16 u16x8 __attribute__((ext_vector_type(8)));
typedef unsigned int u32;
typedef u32 u32x4 __attribute__((ext_vector_type(4)));
typedef const __attribute__((address_space(1))) u32* gp1_t;
typedef __attribute__((address_space(3))) u32* lp3_t;

static __device__ __forceinline__ u16 f2bf(float f) {
  union { float f; unsigned int u; } v; v.f = f;
  unsigned int u = v.u;
  unsigned int r = u + 0x7FFFu + ((u >> 16) & 1u);  // RNE
  return (u16)(r >> 16);
}

// ============================================================================
// Pre-pass: enc [S,B,2H] fp32 -> fragment-ordered tiles per (b,chunk):
//   KH (fp16):  [kb 0..15][lane(m,g)][j] = K[s=m][h=kb*16+g*8+j]   (QK A-op)
//   VT (bf16):  [ht*2+ka][lane][j]      = K[s=ka*16+g*8+j][h=ht*32+m] (PV B-op)
// Each block handles HALF a tile (16 s-rows) -> 2048 blocks, 16.6 KB LDS.
// ============================================================================
__global__ __launch_bounds__(256, 8)
void prepass_kernel(const float* __restrict__ e,
                    u16* __restrict__ KH, u16* __restrict__ VT) {
  __shared__ float Ks[16 * KSTRIDE];   // 16 rows only: 16,640 B
  const int tid = threadIdx.x;
  const int bid = blockIdx.x;
  const int h2  = bid & 1;             // which 16-row half of the chunk
  const int tb  = bid >> 1;            // tile id 0..1023
  const int b   = tb >> 6;
  const int ck  = tb & 63;
  const size_t tile = (size_t)tb * TILE_U16;
  const int r0 = h2 * 16;

  {
    int row = tid >> 4;                // 0..15
    int c16 = tid & 15;                // 0..15
    const float* src = e + ((size_t)(ck * SCHUNK + r0 + row) * BATCH + b) * (2 * HDIM);
#pragma unroll
    for (int u = 0; u < 4; ++u) {
      int col = c16 * 4 + 64 * u;
      float4 xa = *(const float4*)(src + col);
      float4 xb = *(const float4*)(src + col + HDIM);
      float4 s; s.x = xa.x + xb.x; s.y = xa.y + xb.y; s.z = xa.z + xb.z; s.w = xa.w + xb.w;
      *(float4*)&Ks[row * KSTRIDE + col] = s;
    }
  }
  __syncthreads();

  const int lane = tid & 63;
  const int w = tid >> 6;              // 0..3

  // ---- KH: wave w covers kb = 4w + 2i + (lane>=32); our block owns m in [r0,r0+16)
  {
    int half = lane >> 5;
    int l5   = lane & 31;
    int lm   = l5 & 15;                // m - r0
    int g    = (l5 >> 4) & 1;
#pragma unroll
    for (int i = 0; i < 2; ++i) {
      int kb = w * 4 + i * 2 + half;
      const float* rp = &Ks[lm * KSTRIDE + kb * 16 + g * 8];
      u16x8 hi;
#pragma unroll
      for (int j = 0; j < 8; ++j)
        hi[j] = __builtin_bit_cast(u16, (_Float16)rp[j]);
      int lane_out = g * 32 + r0 + lm;
      *(u16x8*)&KH[tile + (size_t)(kb * 64 + lane_out) * 8] = hi;
    }
  }

  // ---- VT: our block owns exactly ka = h2; wave w covers ht = 2w + i
  {
    int m = lane & 31;
    int g = lane >> 5;
#pragma unroll
    for (int i = 0; i < 2; ++i) {
      int ht = w * 2 + i;
      int fr = ht * 2 + h2;
      u16x8 v;
#pragma unroll
      for (int j = 0; j < 8; ++j)
        v[j] = f2bf(Ks[(g * 8 + j) * KSTRIDE + ht * 32 + m]);
      *(u16x8*)&VT[tile + (size_t)(fr * 64 + lane) * 8] = v;
    }
  }
}

// ============================================================================
// Main: 512 threads (8 waves, 1 block/CU). Source-split: waves 0-3 even
// chunks, 4-7 odd chunks, same 128 targets.
// NEW this round:
//  (T12) P never touches LDS: cvt_pk_bf16 + v_permlane32_swap_b32 build the
//        PV A-fragments in registers (kills the Pb roundtrip latency chain
//        and ALL LDS bank conflicts; frees 20 KB LDS).
//  (pipeline) per iter j: [vmcnt(0); s_barrier] -> stage(j+2) ->
//        QK_{j+1} (16 MFMA) || PV_j (16 MFMA, indep) -> SM_{j+1} (VALU,
//        overlaps in-flight PV MFMAs). ONE barrier per iteration.
//        Buffers: K = 2 pair-sets (KHs[4]), V = 3 pair-sets (VTs[6]);
//        everything stage(j+2) overwrites was last read >=1 barrier ago.
//  LDS = 64 + 96 KB = exactly 160 KiB.
// ============================================================================
__global__ __launch_bounds__(512, 2)
void attn_main_kernel(const u16* __restrict__ KH, const u16* __restrict__ VT,
                      const float* __restrict__ dq,  // [T, B, H]
                      float* __restrict__ out) {     // [T, B, H]
  __shared__ alignas(16) u16 KHs[4][TILE_U16];   // 64 KB : K pair-sets {0,1},{2,3}
  __shared__ alignas(16) u16 VTs[6][TILE_U16];   // 96 KB : V pair-sets rotate mod 3

  const int tid  = threadIdx.x;
  const int lane = tid & 63;
  const int wv   = tid >> 6;        // 0..7
  const int wq   = wv & 3;          // target-group 0..3
  const int grp  = wv >> 2;         // 0 = even chunks, 1 = odd chunks
  const int m    = lane & 31;
  const int g    = lane >> 5;

  // XCD-aware swizzle: XCD x gets batches {2x, 2x+1}: K/V set = 4MB ~= L2.
  const int bid = blockIdx.x;
  const int b  = ((bid & 7) << 1) | ((bid >> 3) & 1);
  const int t0 = (bid >> 4) * TTILE;

  // ---- Q fragments fp16 (B-operand: B[k=g*8+j][n=m]) ----
  const int tq = t0 + wq * 32 + m;
  const float* qp = dq + ((size_t)tq * BATCH + b) * HDIM;
  f16x8 qh[16];
#pragma unroll
  for (int kb = 0; kb < 16; ++kb) {
    int h = kb * 16 + g * 8;
    float4 f0 = *(const float4*)(qp + h);
    float4 f1 = *(const float4*)(qp + h + 4);
    float xs[8] = {f0.x, f0.y, f0.z, f0.w, f1.x, f1.y, f1.z, f1.w};
    u16x8 hb;
#pragma unroll
    for (int j = 0; j < 8; ++j)
      hb[j] = __builtin_bit_cast(u16, (_Float16)xs[j]);
    qh[kb] = __builtin_bit_cast(f16x8, hb);
  }

  f32x16 ctx[8];
#pragma unroll
  for (int ht = 0; ht < 8; ++ht) ctx[ht] = (f32x16)(0.0f);
  float dsum = 0.0f;
  bf16x8 pa0 = {}, pa1 = {};     // P fragments for the pending PV (registers!)

  // ---- staging: wave wv owns 8 KB of a pair's 32 KB stage ----
  // wv 0,1: KH chunk 2p | wv 2,3: VT 2p | wv 4,5: KH 2p+1 | wv 6,7: VT 2p+1
  const bool isVT  = (wv >> 1) & 1;
  const int  choff = wv >> 2;
  const int  subbase = (wv & 1) * 8;
  const u16* srcArr = isVT ? VT : KH;
  auto stage = [&](int p) {                 // stage pair p
    int ckk = 2 * p + choff;
    int ktile = 2 * (p & 1) + choff;        // K: 2 pair-sets
    int vtile = (p % 3) * 2 + choff;        // V: 3 pair-sets
    size_t tb = ((size_t)b * NCHUNK + ckk) * TILE_U16;
    u16* dst = isVT ? &VTs[vtile][0] : &KHs[ktile][0];
#pragma unroll
    for (int i = 0; i < 8; ++i) {
      int sub = subbase + i;
      __builtin_amdgcn_global_load_lds(
          (gp1_t)(const void*)&srcArr[tb + (size_t)sub * 512 + lane * 8],
          (lp3_t)(void*)&dst[sub * 512], 16, 0, 0);
    }
  };

  // QK^T as S^T (m=s, n=t) for pair p, fp16, two independent chains
  auto qk = [&](int p, f32x16& a0, f32x16& a1) {
    int kt = 2 * (p & 1) + grp;
#pragma unroll
    for (int kb = 0; kb < 16; kb += 2) {
      f16x8 k0 = __builtin_bit_cast(f16x8, *(const u16x8*)&KHs[kt][kb * 512 + lane * 8]);
      f16x8 k1 = __builtin_bit_cast(f16x8, *(const u16x8*)&KHs[kt][(kb + 1) * 512 + lane * 8]);
      a0 = __builtin_amdgcn_mfma_f32_32x32x16_f16(k0, qh[kb], a0, 0, 0, 0);
      a1 = __builtin_amdgcn_mfma_f32_32x32x16_f16(k1, qh[kb + 1], a1, 0, 0, 0);
    }
  };

  // PV for pair p using register P fragments pa0/pa1
  auto pv = [&](int p) {
    int vt_ = (p % 3) * 2 + grp;
#pragma unroll
    for (int ht = 0; ht < 8; ++ht) {
      bf16x8 v0 = __builtin_bit_cast(bf16x8, *(const u16x8*)&VTs[vt_][(ht * 2) * 512 + lane * 8]);
      bf16x8 v1 = __builtin_bit_cast(bf16x8, *(const u16x8*)&VTs[vt_][(ht * 2 + 1) * 512 + lane * 8]);
      ctx[ht] = __builtin_amdgcn_mfma_f32_32x32x16_bf16(pa0, v0, ctx[ht], 0, 0, 0);
      ctx[ht] = __builtin_amdgcn_mfma_f32_32x32x16_bf16(pa1, v1, ctx[ht], 0, 0, 0);
    }
  };

  // exp(s-128) -> dsum; pack to bf16 pairs; permlane32_swap builds A-frags.
  // C-layout: lane(m,g) holds s = (r&3)+8*(r>>2)+4g for t=m.
  // A-frag needs s = g*8+j (pa0) / 16+g*8+j (pa1): the missing halves live
  // in the partner lane (l^32). v_permlane32_swap_b32 a,b:
  //   a <- {a.lo32lanes, b.lo32lanes}, b <- {a.hi32lanes, b.hi32lanes}
  auto softmax_pack = [&](const f32x16& a0, const f32x16& a1) {
    float pf[16];
#pragma unroll
    for (int r = 0; r < 16; ++r) {
      pf[r] = __expf(a0[r] + a1[r] - 128.0f);
      dsum += pf[r];
    }
    u32 c[8];
#pragma unroll
    for (int q = 0; q < 8; ++q)
      asm("v_cvt_pk_bf16_f32 %0, %1, %2"
          : "=v"(c[q]) : "v"(pf[2 * q]), "v"(pf[2 * q + 1]));
    asm("v_permlane32_swap_b32 %0, %1" : "+v"(c[0]), "+v"(c[2]));
    asm("v_permlane32_swap_b32 %0, %1" : "+v"(c[1]), "+v"(c[3]));
    asm("v_permlane32_swap_b32 %0, %1" : "+v"(c[4]), "+v"(c[6]));
    asm("v_permlane32_swap_b32 %0, %1" : "+v"(c[5]), "+v"(c[7]));
    u32x4 w0 = {c[0], c[1], c[2], c[3]};
    u32x4 w1 = {c[4], c[5], c[6], c[7]};
    pa0 = __builtin_bit_cast(bf16x8, w0);
    pa1 = __builtin_bit_cast(bf16x8, w1);
  };

  // ---- prologue: stage pairs 0,1; QK_0 + SM_0 ----
  stage(0);
  stage(1);
  asm volatile("s_waitcnt vmcnt(8)" ::: "memory");  // pair 0 landed; pair 1 in flight
  __builtin_amdgcn_s_barrier();
  {
    f32x16 a0 = (f32x16)(0.0f), a1 = (f32x16)(0.0f);
    qk(0, a0, a1);
    softmax_pack(a0, a1);
  }

  // ---- main loop: QK_{j+1} || PV_j, one barrier per iter ----
  for (int j = 0; j < 32; ++j) {
    asm volatile("s_waitcnt vmcnt(0)" ::: "memory"); // stage(j+1) landed
    __builtin_amdgcn_s_barrier();
    if (j < 30) stage(j + 2);

    f32x16 a0 = (f32x16)(0.0f), a1 = (f32x16)(0.0f);
    __builtin_amdgcn_s_setprio(1);
    if (j < 31) qk(j + 1, a0, a1);   // independent of PV below
    pv(j);                           // consumes pa0/pa1 from previous SM
    __builtin_amdgcn_s_setprio(0);
    if (j < 31) softmax_pack(a0, a1);  // overlaps in-flight PV MFMAs
  }

  // ---- combine the two source-halves (exact: same exp offset) ----
  dsum += __shfl_xor(dsum, 32, 64);   // per-lane: partial denom for t = m
  __syncthreads();                     // full drain once; bufs reusable

  // exchange regions (32 KB per target-group) carved from KHs/VTs
  float* exch = (wq == 0) ? (float*)&KHs[0][0]
              : (wq == 1) ? (float*)&KHs[2][0]
              : (wq == 2) ? (float*)&VTs[0][0]
                          : (float*)&VTs[2][0];
  float* dex = (float*)&VTs[4][0];   // denom exchange (1 KB)

  if (grp == 1) {
    // layout [r4][ht][lane][4]: b128, 2-way banks (free)
#pragma unroll
    for (int r4 = 0; r4 < 4; ++r4)
#pragma unroll
      for (int ht = 0; ht < 8; ++ht) {
        f32x4 v = {ctx[ht][r4 * 4], ctx[ht][r4 * 4 + 1],
                   ctx[ht][r4 * 4 + 2], ctx[ht][r4 * 4 + 3]};
        *(f32x4*)&exch[r4 * 2048 + ht * 256 + lane * 4] = v;
      }
    dex[wq * 64 + lane] = dsum;
  }
  __syncthreads();

  if (grp == 0) {
    float dB = dex[wq * 64 + lane];
    float inv = 1.0f / (dsum + dB);
#pragma unroll
    for (int r4 = 0; r4 < 4; ++r4)
#pragma unroll
      for (int ht = 0; ht < 8; ++ht) {
        f32x4 v = *(const f32x4*)&exch[r4 * 2048 + ht * 256 + lane * 4];
        ctx[ht][r4 * 4]     += v[0];
        ctx[ht][r4 * 4 + 1] += v[1];
        ctx[ht][r4 * 4 + 2] += v[2];
        ctx[ht][r4 * 4 + 3] += v[3];
      }
#pragma unroll
    for (int r = 0; r < 16; ++r) {
      int tl = (r & 3) + 8 * (r >> 2) + 4 * g;
      float rinv = __shfl(inv, tl, 64);
      int t = t0 + wq * 32 + tl;
      float* op = out + ((size_t)t * BATCH + b) * HDIM + m;
#pragma unroll
      for (int ht = 0; ht < 8; ++ht)
        op[ht * 32] = ctx[ht][r] * rinv;
    }
  }
}

extern "C" void kernel_launch(void* const* d_in, const int* in_sizes, int n_in,
                              void* d_out, int out_size, void* d_ws, size_t ws_size,
                              hipStream_t stream) {
  const float* e  = (const float*)d_in[0];  // out_e [2048, 16, 512]
  const float* dq = (const float*)d_in[1];  // out_d [2048, 16, 256]
  float* out = (float*)d_out;               // [2048, 16, 256]
  u16* KH = (u16*)d_ws;                                 // fp16 bits, 16 MB
  u16* VT = KH + (size_t)NTILES * TILE_U16;             // bf16 bits, 16 MB
  prepass_kernel<<<dim3(PREBLK), dim3(256), 0, stream>>>(e, KH, VT);
  attn_main_kernel<<<dim3(BATCH * (SEQ / TTILE)), dim3(512), 0, stream>>>(
      KH, VT, dq, out);
}